// Round 1
// baseline (932.104 us; speedup 1.0000x reference)
//
#include <hip/hip_runtime.h>

#define BB 8192
#define LL 40
#define VV 100000
#define ALLF 456
#define NEG_INF_F (-4294967295.0f)

// ---------------- prep kernels ----------------

__device__ __forceinline__ unsigned short f2bf(float f) {
  unsigned u = __float_as_uint(f);
  u += 0x7FFFu + ((u >> 16) & 1u);
  return (unsigned short)(u >> 16);
}

// Combined+transposed attention layer-1 weights, row stride 132 floats.
// wsdT[h][k] = W1[128+k][h] - W1[256+k][h]   (multiplies s)
// wpT [h][k] = W1[384+k][h]                  (multiplies q*s)
// wqcT[h][k] = W1[k][h]     + W1[256+k][h]   (multiplies q, const over L)
__global__ void prep_att(const float* __restrict__ W1,
                         float* __restrict__ wsdT, float* __restrict__ wpT,
                         float* __restrict__ wqcT) {
  int i = blockIdx.x * blockDim.x + threadIdx.x;
  if (i >= 80 * 128) return;
  int h = i >> 7, k = i & 127;
  float a = W1[k * 80 + h];
  float b = W1[(128 + k) * 80 + h];
  float c = W1[(256 + k) * 80 + h];
  float d = W1[(384 + k) * 80 + h];
  wsdT[h * 132 + k] = b - c;
  wpT[h * 132 + k]  = d;
  wqcT[h * 132 + k] = a + c;
}

// Fold inference BatchNorm into FFN layer 1; store weights bf16.
__global__ void prep_ffn(const float* __restrict__ W1, const float* __restrict__ b1,
                         const float* __restrict__ g,  const float* __restrict__ be,
                         const float* __restrict__ mn, const float* __restrict__ vr,
                         unsigned short* __restrict__ W1b, float* __restrict__ b1p) {
  int h = threadIdx.x + blockIdx.x * blockDim.x;
  if (h >= 80) return;
  float acc = b1[h];
  for (int k = 0; k < ALLF; k++) {
    float sc = g[k] * rsqrtf(vr[k] + 1e-3f);
    float w = W1[k * 80 + h];
    W1b[k * 80 + h] = f2bf(w * sc);
    acc += (be[k] - mn[k] * sc) * w;
  }
  b1p[h] = acc;
}

// ---------------- main fused kernel: one block per batch row ----------------

__launch_bounds__(320, 4)
__global__ void din_main(const float* __restrict__ dense, const int* __restrict__ sparsei,
                         const int* __restrict__ seqi, const int* __restrict__ itemi,
                         const float* __restrict__ embS, const float* __restrict__ embQ,
                         const float* __restrict__ wsdT, const float* __restrict__ wpT,
                         const float* __restrict__ wqcT,
                         const float* __restrict__ ab1, const float* __restrict__ aW2,
                         const float* __restrict__ ab2, const float* __restrict__ aWf,
                         const float* __restrict__ abf,
                         const unsigned short* __restrict__ W1b, const float* __restrict__ b1p,
                         const float* __restrict__ fa1, const float* __restrict__ fW2,
                         const float* __restrict__ fb2, const float* __restrict__ fa2,
                         const float* __restrict__ oW, const float* __restrict__ ob,
                         float* __restrict__ out) {
  __shared__ float sS[40 * 132];   // seq_embed, padded stride 132
  __shared__ float sQ[128];        // item embed
  __shared__ float sQW[80];        // q-part of layer1 (+bias)
  __shared__ float sH1[40 * 80];   // layer1 sigmoid out
  __shared__ float sH2[40 * 40];   // layer2 sigmoid out
  __shared__ float sAtt[40];       // softmax weights
  __shared__ float sX[456];        // info_all
  __shared__ float sF1[80];
  __shared__ float sF2[40];

  const int t = threadIdx.x;       // 0..319
  const int b = blockIdx.x;        // batch row

  // ---- gather q (item) : 2 rows x 64 floats ----
  if (t < 32) {
    int f = t >> 4, sub = t & 15;
    int idx = itemi[b * 2 + f];
    float4 v = *(const float4*)(embQ + ((size_t)(f * VV + idx)) * 64 + sub * 4);
    *(float4*)(sQ + f * 64 + sub * 4) = v;
  }
  // ---- gather seq tile: 80 rows x 64 floats, 16 float4 per row ----
  for (int i = t; i < 80 * 16; i += 320) {
    int r = i >> 4, sub = i & 15;
    int l = r >> 1, f = r & 1;
    int idx = seqi[(b * LL + l) * 2 + f];
    float4 v = *(const float4*)(embQ + ((size_t)(f * VV + idx)) * 64 + sub * 4);
    *(float4*)(sS + l * 132 + f * 64 + sub * 4) = v;
  }
  __syncthreads();

  // ---- q-part of layer1 (constant over L) ----
  if (t < 80) {
    float acc = ab1[t];
    const float* wq = wqcT + t * 132;
    for (int k = 0; k < 128; k += 4) {
      float4 w = *(const float4*)(wq + k);
      float4 q = *(const float4*)(sQ + k);
      acc += q.x * w.x + q.y * w.y + q.z * w.z + q.w * w.w;
    }
    sQW[t] = acc;
  }
  __syncthreads();

  // ---- layer1 main: h1[l][h] over 40x80, K=128 (s part) + 128 (q*s part) ----
  {
    const int hg = t >> 3;          // 0..39 -> h pair
    const int lg = t & 7;           // 0..7  -> l = lg + 8*i
    const int h0 = hg * 2;
    float acc0[5] = {0.f, 0.f, 0.f, 0.f, 0.f};
    float acc1[5] = {0.f, 0.f, 0.f, 0.f, 0.f};
    const float* wr0 = wsdT + (size_t)h0 * 132;
    const float* wr1 = wr0 + 132;
    const float* pr0 = wpT + (size_t)h0 * 132;
    const float* pr1 = pr0 + 132;
    for (int k = 0; k < 128; k += 4) {
      float4 qv = *(const float4*)(sQ + k);
      float4 w0 = *(const float4*)(wr0 + k);
      float4 w1 = *(const float4*)(wr1 + k);
      float4 p0 = *(const float4*)(pr0 + k);
      float4 p1 = *(const float4*)(pr1 + k);
#pragma unroll
      for (int i = 0; i < 5; i++) {
        float4 sv = *(const float4*)(sS + (lg + 8 * i) * 132 + k);
        float px = qv.x * sv.x, py = qv.y * sv.y, pz = qv.z * sv.z, pw = qv.w * sv.w;
        acc0[i] += sv.x * w0.x + sv.y * w0.y + sv.z * w0.z + sv.w * w0.w
                 + px * p0.x + py * p0.y + pz * p0.z + pw * p0.w;
        acc1[i] += sv.x * w1.x + sv.y * w1.y + sv.z * w1.z + sv.w * w1.w
                 + px * p1.x + py * p1.y + pz * p1.z + pw * p1.w;
      }
    }
    float qw0 = sQW[h0], qw1 = sQW[h0 + 1];
#pragma unroll
    for (int i = 0; i < 5; i++) {
      int l = lg + 8 * i;
      float z0 = acc0[i] + qw0;
      float z1 = acc1[i] + qw1;
      sH1[l * 80 + h0]     = 1.f / (1.f + __expf(-z0));
      sH1[l * 80 + h0 + 1] = 1.f / (1.f + __expf(-z1));
    }
  }
  __syncthreads();

  // ---- layer2: h2[l][j] 40x40, K=80 ----
  {
    const int j = t % 40;
    const int lg2 = t / 40;         // 0..7
    float acc[5] = {0.f, 0.f, 0.f, 0.f, 0.f};
    for (int h = 0; h < 80; h++) {
      float wv = aW2[h * 40 + j];
#pragma unroll
      for (int i = 0; i < 5; i++) acc[i] += sH1[(lg2 + 8 * i) * 80 + h] * wv;
    }
    float bb = ab2[j];
#pragma unroll
    for (int i = 0; i < 5; i++) {
      float z = acc[i] + bb;
      sH2[(lg2 + 8 * i) * 40 + j] = 1.f / (1.f + __expf(-z));
    }
  }
  __syncthreads();

  // ---- logits + mask + softmax (wave 0) ----
  if (t < 64) {
    float logit = -3.0e38f;
    if (t < 40) {
      float acc = abf[0];
      for (int j = 0; j < 40; j++) acc += sH2[t * 40 + j] * aWf[j];
      bool m = (seqi[(b * LL + t) * 2] != 0);
      logit = m ? acc : NEG_INF_F;
    }
    float mx = logit;
    for (int off = 32; off; off >>= 1) mx = fmaxf(mx, __shfl_xor(mx, off, 64));
    float ex = (t < 40) ? __expf(logit - mx) : 0.f;
    float sm = ex;
    for (int off = 32; off; off >>= 1) sm += __shfl_xor(sm, off, 64);
    if (t < 40) sAtt[t] = ex / sm;
  }
  __syncthreads();

  // ---- pooled user_info + concat info_all ----
  if (t < 128) {
    float acc = 0.f;
    for (int l = 0; l < 40; l++) acc += sAtt[l] * sS[l * 132 + t];
    sX[t] = acc;
  }
  for (int i = t + 128; i < ALLF; i += 320) {
    float v;
    if (i < 256) {
      v = sQ[i - 128];
    } else if (i < 264) {
      v = dense[b * 8 + (i - 256)];
    } else {
      int f = (i - 264) >> 6, e = (i - 264) & 63;
      int idx = sparsei[b * 3 + f];
      v = embS[((size_t)(f * VV + idx)) * 64 + e];
    }
    sX[i] = v;
  }
  __syncthreads();

  // ---- FFN layer1 (BN folded, bf16 weights) ----
  if (t < 80) {
    float acc = b1p[t];
#pragma unroll 8
    for (int k = 0; k < ALLF; k++) {
      float w = __uint_as_float(((unsigned)W1b[k * 80 + t]) << 16);
      acc += sX[k] * w;
    }
    sF1[t] = acc > 0.f ? acc : fa1[t] * acc;
  }
  __syncthreads();

  // ---- FFN layer2 ----
  if (t < 40) {
    float acc = fb2[t];
#pragma unroll 8
    for (int h = 0; h < 80; h++) acc += sF1[h] * fW2[h * 40 + t];
    sF2[t] = acc > 0.f ? acc : fa2[t] * acc;
  }
  __syncthreads();

  // ---- output dot(40) + sigmoid ----
  if (t < 64) {
    float v = (t < 40) ? sF2[t] * oW[t] : 0.f;
    for (int off = 32; off; off >>= 1) v += __shfl_xor(v, off, 64);
    if (t == 0) out[b] = 1.f / (1.f + __expf(-(v + ob[0])));
  }
}

// ---------------- launch ----------------

extern "C" void kernel_launch(void* const* d_in, const int* in_sizes, int n_in,
                              void* d_out, int out_size, void* d_ws, size_t ws_size,
                              hipStream_t stream) {
  const float* dense  = (const float*)d_in[0];
  const int*   sparsei = (const int*)d_in[1];
  const int*   seqi   = (const int*)d_in[2];
  const int*   itemi  = (const int*)d_in[3];
  const float* embS   = (const float*)d_in[4];
  const float* embQ   = (const float*)d_in[5];
  const float* aW1    = (const float*)d_in[6];
  const float* ab1    = (const float*)d_in[7];
  const float* aW2    = (const float*)d_in[8];
  const float* ab2    = (const float*)d_in[9];
  const float* aWf    = (const float*)d_in[10];
  const float* abf    = (const float*)d_in[11];
  const float* bng    = (const float*)d_in[12];
  const float* bnb    = (const float*)d_in[13];
  const float* bnm    = (const float*)d_in[14];
  const float* bnv    = (const float*)d_in[15];
  const float* fW1    = (const float*)d_in[16];
  const float* fb1    = (const float*)d_in[17];
  const float* fa1    = (const float*)d_in[18];
  const float* fW2    = (const float*)d_in[19];
  const float* fb2    = (const float*)d_in[20];
  const float* fa2    = (const float*)d_in[21];
  const float* oW     = (const float*)d_in[22];
  const float* ob     = (const float*)d_in[23];
  float* out = (float*)d_out;

  float* ws = (float*)d_ws;
  float* wsdT = ws;                 // 80*132
  float* wpT  = ws + 10560;         // 80*132
  float* wqcT = ws + 21120;         // 80*132
  unsigned short* W1b = (unsigned short*)(ws + 31680);  // 456*80 shorts
  float* b1p = ws + 31680 + 18240;  // 80 floats

  prep_att<<<40, 256, 0, stream>>>(aW1, wsdT, wpT, wqcT);
  prep_ffn<<<1, 128, 0, stream>>>(fW1, fb1, bng, bnb, bnm, bnv, W1b, b1p);
  din_main<<<BB, 320, 0, stream>>>(dense, sparsei, seqi, itemi, embS, embQ,
                                   wsdT, wpT, wqcT, ab1, aW2, ab2, aWf, abf,
                                   W1b, b1p, fa1, fW2, fb2, fa2, oW, ob, out);
}

// Round 2
// 586.322 us; speedup vs baseline: 1.5897x; 1.5897x over previous
//
#include <hip/hip_runtime.h>

#define BB 8192
#define LL 40
#define VV 100000
#define ALLF 456
#define NEG_INF_F (-4294967295.0f)

typedef __attribute__((ext_vector_type(8))) short short8;
typedef __attribute__((ext_vector_type(4))) float f32x4;

__device__ __forceinline__ unsigned short f2bf(float f) {
  unsigned u = __float_as_uint(f);
  u += 0x7FFFu + ((u >> 16) & 1u);
  return (unsigned short)(u >> 16);
}
__device__ __forceinline__ float bf2f(unsigned short s) {
  return __uint_as_float(((unsigned)s) << 16);
}

// ---------------- prep kernels ----------------

// wqcT fp32 [80][132]: q-coefficient (W1a + W1c), for fp32 qconst dot.
// WsdpT bf16 [80 n][256 k]: k<128 -> (W1b - W1c) (multiplies s);
//                           k>=128 -> W1d (multiplies q*s).
__global__ void prep_att(const float* __restrict__ W1,
                         float* __restrict__ wqcT,
                         unsigned short* __restrict__ WsdpT) {
  int i = blockIdx.x * blockDim.x + threadIdx.x;
  if (i >= 80 * 128) return;
  int h = i >> 7, k = i & 127;
  float a = W1[k * 80 + h];
  float b = W1[(128 + k) * 80 + h];
  float c = W1[(256 + k) * 80 + h];
  float d = W1[(384 + k) * 80 + h];
  wqcT[h * 132 + k] = a + c;
  WsdpT[h * 256 + k] = f2bf(b - c);
  WsdpT[h * 256 + 128 + k] = f2bf(d);
}

// W2bT bf16 [48 n][96 k], zero-padded (n>=40 or k>=80 -> 0).
__global__ void prep_w2(const float* __restrict__ W2,
                        unsigned short* __restrict__ W2bT) {
  int i = blockIdx.x * blockDim.x + threadIdx.x;
  if (i >= 48 * 96) return;
  int n = i / 96, k = i % 96;
  float v = (n < 40 && k < 80) ? W2[k * 40 + n] : 0.f;
  W2bT[i] = f2bf(v);
}

// Fold inference BatchNorm into FFN layer 1; store weights bf16.
__global__ void prep_ffn(const float* __restrict__ W1, const float* __restrict__ b1,
                         const float* __restrict__ g,  const float* __restrict__ be,
                         const float* __restrict__ mn, const float* __restrict__ vr,
                         unsigned short* __restrict__ W1b, float* __restrict__ b1p) {
  int h = threadIdx.x + blockIdx.x * blockDim.x;
  if (h >= 80) return;
  float acc = b1[h];
  for (int k = 0; k < ALLF; k++) {
    float sc = g[k] * rsqrtf(vr[k] + 1e-3f);
    float w = W1[k * 80 + h];
    W1b[k * 80 + h] = f2bf(w * sc);
    acc += (be[k] - mn[k] * sc) * w;
  }
  b1p[h] = acc;
}

// ---------------- main fused kernel: one block per batch row ----------------

#define XS 264   // X row stride (bf16 elems): 256 + 8 pad
#define HS 104   // H1 row stride (bf16 elems): 96 + 8 pad

__launch_bounds__(256, 3)
__global__ void din_main(const float* __restrict__ dense, const int* __restrict__ sparsei,
                         const int* __restrict__ seqi, const int* __restrict__ itemi,
                         const float* __restrict__ embS, const float* __restrict__ embQ,
                         const float* __restrict__ wqcT, const unsigned short* __restrict__ WsdpT,
                         const unsigned short* __restrict__ W2bT,
                         const float* __restrict__ ab1, const float* __restrict__ ab2,
                         const float* __restrict__ aWf, const float* __restrict__ abf,
                         const unsigned short* __restrict__ W1b, const float* __restrict__ b1p,
                         const float* __restrict__ fa1, const float* __restrict__ fW2,
                         const float* __restrict__ fb2, const float* __restrict__ fa2,
                         const float* __restrict__ oW, const float* __restrict__ ob,
                         float* __restrict__ out) {
  __shared__ __align__(16) unsigned short sX[48 * XS];   // [s | q*s] bf16
  __shared__ __align__(16) unsigned short sH1[48 * HS];  // layer1 out bf16 (K2-padded)
  __shared__ float sQ[128];       // item embed fp32
  __shared__ float sQC[80];       // qconst = b1 + q·(Wa+Wc)
  __shared__ float sH2T[40 * 44]; // layer2 out, [j][l]
  __shared__ float sAtt[40];
  __shared__ float sXall[456];
  __shared__ float sF1p[160];
  __shared__ float sF1[80];
  __shared__ float sF2[40];

  const int t = threadIdx.x;   // 0..255
  const int b = blockIdx.x;

  // ---- phase 1: gathers + zeroing ----
  if (t < 32) {
    int f = t >> 4, sub = t & 15;
    int idx = itemi[b * 2 + f];
    float4 v = *(const float4*)(embQ + ((size_t)(f * VV + idx)) * 64 + sub * 4);
    *(float4*)(sQ + f * 64 + sub * 4) = v;
  }
  for (int i = t; i < 80 * 16; i += 256) {
    int r = i >> 4, sub = i & 15;
    int l = r >> 1, f = r & 1;
    int idx = seqi[(b * LL + l) * 2 + f];
    float4 v = *(const float4*)(embQ + ((size_t)(f * VV + idx)) * 64 + sub * 4);
    ushort4 u;
    u.x = f2bf(v.x); u.y = f2bf(v.y); u.z = f2bf(v.z); u.w = f2bf(v.w);
    *(ushort4*)(sX + l * XS + f * 64 + sub * 4) = u;
  }
  {
    // zero X rows 40..47 (incl pads)
    unsigned* x32 = (unsigned*)(sX + 40 * XS);
    for (int i = t; i < 8 * XS / 2; i += 256) x32[i] = 0u;
    // zero H1 cols 80..95 for all 48 rows (K2 pad)
    for (int i = t; i < 48 * 8; i += 256) {
      int r = i >> 3, c = i & 7;
      ((unsigned*)sH1)[r * (HS / 2) + 40 + c] = 0u;
    }
  }
  __syncthreads();

  // ---- phase 2: qconst (fp32) + q*s product (bf16) ----
  if (t < 80) {
    float acc = ab1[t];
    const float* wq = wqcT + t * 132;
    for (int k = 0; k < 128; k += 4) {
      float4 w = *(const float4*)(wq + k);
      float4 q = *(const float4*)(sQ + k);
      acc += q.x * w.x + q.y * w.y + q.z * w.z + q.w * w.w;
    }
    sQC[t] = acc;
  }
  for (int i = t; i < 40 * 128; i += 256) {
    int l = i >> 7, k = i & 127;
    float sv = bf2f(sX[l * XS + k]);
    sX[l * XS + 128 + k] = f2bf(sQ[k] * sv);
  }
  __syncthreads();

  // ---- phase 3: layer1 MFMA: C[48x80] = X[48x256] · Wsdp[256x80] ----
  const int wv = t >> 6, ln = t & 63;
  const int m16 = ln & 15, quad = ln >> 4;
  for (int tile = wv; tile < 15; tile += 4) {
    int mt = tile / 5, nt = tile % 5;
    f32x4 acc = {0.f, 0.f, 0.f, 0.f};
    const unsigned short* ar = sX + (mt * 16 + m16) * XS + quad * 8;
    const unsigned short* br = WsdpT + (size_t)(nt * 16 + m16) * 256 + quad * 8;
#pragma unroll
    for (int kt = 0; kt < 8; kt++) {
      short8 a = *(const short8*)(ar + kt * 32);
      short8 bfr = *(const short8*)(br + kt * 32);
      acc = __builtin_amdgcn_mfma_f32_16x16x32_bf16(a, bfr, acc, 0, 0, 0);
    }
    int h = nt * 16 + m16;          // C col
    float qc = sQC[h];
#pragma unroll
    for (int r = 0; r < 4; r++) {
      int l = mt * 16 + quad * 4 + r;  // C row
      float z = acc[r] + qc;
      float hv = 1.f / (1.f + __expf(-z));
      sH1[l * HS + h] = f2bf(hv);
    }
  }
  __syncthreads();

  // ---- phase 4: layer2 MFMA: C[48x48] = H1[48x96] · W2[96x48] ----
  for (int tile = wv; tile < 9; tile += 4) {
    int mt = tile / 3, nt = tile % 3;
    f32x4 acc = {0.f, 0.f, 0.f, 0.f};
    const unsigned short* ar = sH1 + (mt * 16 + m16) * HS + quad * 8;
    const unsigned short* br = W2bT + (size_t)(nt * 16 + m16) * 96 + quad * 8;
#pragma unroll
    for (int kt = 0; kt < 3; kt++) {
      short8 a = *(const short8*)(ar + kt * 32);
      short8 bfr = *(const short8*)(br + kt * 32);
      acc = __builtin_amdgcn_mfma_f32_16x16x32_bf16(a, bfr, acc, 0, 0, 0);
    }
    int j = nt * 16 + m16;
    if (j < 40) {
      float bb = ab2[j];
#pragma unroll
      for (int r = 0; r < 4; r++) {
        int l = mt * 16 + quad * 4 + r;
        if (l < 40) {
          float z = acc[r] + bb;
          sH2T[j * 44 + l] = 1.f / (1.f + __expf(-z));
        }
      }
    }
  }
  __syncthreads();

  // ---- phase 5: logits + mask + softmax (wave 0) ----
  if (t < 64) {
    float logit = -3.0e38f;
    if (t < 40) {
      float acc = abf[0];
      for (int j = 0; j < 40; j++) acc += sH2T[j * 44 + t] * aWf[j];
      bool m = (seqi[(b * LL + t) * 2] != 0);
      logit = m ? acc : NEG_INF_F;
    }
    float mx = logit;
    for (int off = 32; off; off >>= 1) mx = fmaxf(mx, __shfl_xor(mx, off, 64));
    float ex = (t < 40) ? __expf(logit - mx) : 0.f;
    float sm = ex;
    for (int off = 32; off; off >>= 1) sm += __shfl_xor(sm, off, 64);
    if (t < 40) sAtt[t] = ex / sm;
  }
  __syncthreads();

  // ---- phase 6: pooled user_info + concat info_all ----
  if (t < 128) {
    float acc = 0.f;
    for (int l = 0; l < 40; l++) acc += sAtt[l] * bf2f(sX[l * XS + t]);
    sXall[t] = acc;
  }
  for (int i = t + 128; i < ALLF; i += 256) {
    float v;
    if (i < 256) {
      v = sQ[i - 128];
    } else if (i < 264) {
      v = dense[b * 8 + (i - 256)];
    } else {
      int f = (i - 264) >> 6, e = (i - 264) & 63;
      int idx = sparsei[b * 3 + f];
      v = embS[((size_t)(f * VV + idx)) * 64 + e];
    }
    sXall[i] = v;
  }
  __syncthreads();

  // ---- phase 7: FFN layer1 (BN folded, bf16 weights), split-K over 2 ----
  if (t < 160) {
    int h = t % 80, piece = t / 80;
    int k0 = piece * 228;
    float acc = 0.f;
#pragma unroll 4
    for (int k = k0; k < k0 + 228; k++) acc += sXall[k] * bf2f(W1b[k * 80 + h]);
    sF1p[t] = acc;
  }
  __syncthreads();
  if (t < 80) {
    float acc = b1p[t] + sF1p[t] + sF1p[80 + t];
    sF1[t] = acc > 0.f ? acc : fa1[t] * acc;
  }
  __syncthreads();

  // ---- phase 8: FFN layer2 ----
  if (t < 40) {
    float acc = fb2[t];
#pragma unroll 8
    for (int h = 0; h < 80; h++) acc += sF1[h] * fW2[h * 40 + t];
    sF2[t] = acc > 0.f ? acc : fa2[t] * acc;
  }
  __syncthreads();

  // ---- output dot(40) + sigmoid ----
  if (t < 64) {
    float v = (t < 40) ? sF2[t] * oW[t] : 0.f;
    for (int off = 32; off; off >>= 1) v += __shfl_xor(v, off, 64);
    if (t == 0) out[b] = 1.f / (1.f + __expf(-(v + ob[0])));
  }
}

// ---------------- launch ----------------

extern "C" void kernel_launch(void* const* d_in, const int* in_sizes, int n_in,
                              void* d_out, int out_size, void* d_ws, size_t ws_size,
                              hipStream_t stream) {
  const float* dense  = (const float*)d_in[0];
  const int*   sparsei = (const int*)d_in[1];
  const int*   seqi   = (const int*)d_in[2];
  const int*   itemi  = (const int*)d_in[3];
  const float* embS   = (const float*)d_in[4];
  const float* embQ   = (const float*)d_in[5];
  const float* aW1    = (const float*)d_in[6];
  const float* ab1    = (const float*)d_in[7];
  const float* aW2    = (const float*)d_in[8];
  const float* ab2    = (const float*)d_in[9];
  const float* aWf    = (const float*)d_in[10];
  const float* abf    = (const float*)d_in[11];
  const float* bng    = (const float*)d_in[12];
  const float* bnb    = (const float*)d_in[13];
  const float* bnm    = (const float*)d_in[14];
  const float* bnv    = (const float*)d_in[15];
  const float* fW1    = (const float*)d_in[16];
  const float* fb1    = (const float*)d_in[17];
  const float* fa1    = (const float*)d_in[18];
  const float* fW2    = (const float*)d_in[19];
  const float* fb2    = (const float*)d_in[20];
  const float* fa2    = (const float*)d_in[21];
  const float* oW     = (const float*)d_in[22];
  const float* ob     = (const float*)d_in[23];
  float* out = (float*)d_out;

  float* ws = (float*)d_ws;
  float* wqcT = ws;                                        // 80*132 f
  float* b1p  = ws + 10560;                                // 80 f
  unsigned short* W1b   = (unsigned short*)(ws + 10640);   // 456*80 u16 = 9120 f
  unsigned short* WsdpT = (unsigned short*)(ws + 19760);   // 80*256 u16 = 10240 f
  unsigned short* W2bT  = (unsigned short*)(ws + 30000);   // 48*96 u16  = 1152 f

  prep_att<<<40, 256, 0, stream>>>(aW1, wqcT, WsdpT);
  prep_w2<<<18, 256, 0, stream>>>(aW2, W2bT);
  prep_ffn<<<1, 128, 0, stream>>>(fW1, fb1, bng, bnb, bnm, bnv, W1b, b1p);
  din_main<<<BB, 256, 0, stream>>>(dense, sparsei, seqi, itemi, embS, embQ,
                                   wqcT, WsdpT, W2bT, ab1, ab2, aWf, abf,
                                   W1b, b1p, fa1, fW2, fb2, fa2, oW, ob, out);
}

// Round 3
// 507.890 us; speedup vs baseline: 1.8352x; 1.1544x over previous
//
#include <hip/hip_runtime.h>

#define BB 8192
#define LL 40
#define VV 100000
#define NEG_INF_F (-4294967295.0f)
#define XS 264    // attention A-tile row stride (bf16)
#define HS 104    // H1 row stride (bf16), K padded 80->96
#define XGS 480   // global info_all row stride (bf16), K padded 456->480

typedef __attribute__((ext_vector_type(8))) short short8;
typedef __attribute__((ext_vector_type(4))) float f32x4;

__device__ __forceinline__ unsigned short f2bf(float f) {
  unsigned u = __float_as_uint(f);
  u += 0x7FFFu + ((u >> 16) & 1u);
  return (unsigned short)(u >> 16);
}
__device__ __forceinline__ float bf2f(unsigned short s) {
  return __uint_as_float(((unsigned)s) << 16);
}

// ---------------- prep (fused, parallel) ----------------
// bid<40   : attention W1 -> wqcT fp32[80][132], WsdpT bf16[80][256]
// bid<58   : attention W2 -> W2bT bf16[48][96] (zero-padded)
// bid<76   : ffn W2       -> W2fT bf16[48][96] (zero-padded)
// else     : ffn W1 (BN-folded) -> W1fT bf16[80][480] (k>=456 zero)
__global__ void prep_all(const float* __restrict__ W1, float* __restrict__ wqcT,
                         unsigned short* __restrict__ WsdpT,
                         const float* __restrict__ aW2, unsigned short* __restrict__ W2bT,
                         const float* __restrict__ fW2, unsigned short* __restrict__ W2fT,
                         const float* __restrict__ fW1, const float* __restrict__ g,
                         const float* __restrict__ vr, unsigned short* __restrict__ W1fT) {
  int bid = blockIdx.x, t = threadIdx.x;
  if (bid < 40) {
    int i = bid * 256 + t;           // exactly 10240
    int h = i >> 7, k = i & 127;
    float a = W1[k * 80 + h];
    float b = W1[(128 + k) * 80 + h];
    float c = W1[(256 + k) * 80 + h];
    float d = W1[(384 + k) * 80 + h];
    wqcT[h * 132 + k] = a + c;
    WsdpT[h * 256 + k] = f2bf(b - c);
    WsdpT[h * 256 + 128 + k] = f2bf(d);
  } else if (bid < 58) {
    int i = (bid - 40) * 256 + t;
    if (i < 4608) { int n = i / 96, k = i % 96;
      W2bT[i] = (n < 40 && k < 80) ? f2bf(aW2[k * 40 + n]) : (unsigned short)0; }
  } else if (bid < 76) {
    int i = (bid - 58) * 256 + t;
    if (i < 4608) { int n = i / 96, k = i % 96;
      W2fT[i] = (n < 40 && k < 80) ? f2bf(fW2[k * 40 + n]) : (unsigned short)0; }
  } else {
    int i = (bid - 76) * 256 + t;
    if (i < 38400) { int n = i / 480, k = i % 480;
      float v = 0.f;
      if (k < 456) v = fW1[k * 80 + n] * g[k] * rsqrtf(vr[k] + 1e-3f);
      W1fT[i] = f2bf(v); }
  }
}

// b1p[n] = fb1[n] + sum_k (beta[k]-mean[k]*sc[k]) * W1[k][n]   (parallel reduce)
__global__ void prep_b1p(const float* __restrict__ fW1, const float* __restrict__ fb1,
                         const float* __restrict__ g, const float* __restrict__ be,
                         const float* __restrict__ mn, const float* __restrict__ vr,
                         float* __restrict__ b1p) {
  int n = blockIdx.x, t = threadIdx.x;   // 512 threads
  float p = 0.f;
  if (t < 456) {
    float sc = g[t] * rsqrtf(vr[t] + 1e-3f);
    p = (be[t] - mn[t] * sc) * fW1[t * 80 + n];
  }
  for (int off = 32; off; off >>= 1) p += __shfl_xor(p, off, 64);
  __shared__ float red[8];
  if ((t & 63) == 0) red[t >> 6] = p;
  __syncthreads();
  if (t == 0) {
    float s = fb1[n];
    for (int w = 0; w < 8; w++) s += red[w];
    b1p[n] = s;
  }
}

// ---------------- kernel A: attention + pool, one row per block ----------------

__launch_bounds__(320, 3)
__global__ void din_att(const float* __restrict__ dense, const int* __restrict__ sparsei,
                        const int* __restrict__ seqi, const int* __restrict__ itemi,
                        const float* __restrict__ embS, const float* __restrict__ embQ,
                        const float* __restrict__ wqcT, const unsigned short* __restrict__ WsdpT,
                        const unsigned short* __restrict__ W2bT,
                        const float* __restrict__ ab1, const float* __restrict__ ab2,
                        const float* __restrict__ aWf, const float* __restrict__ abf,
                        unsigned short* __restrict__ Xg) {
  __shared__ __align__(16) unsigned short sX[48 * XS];
  __shared__ __align__(16) unsigned short sH1[48 * HS];
  __shared__ float sQ[128];
  __shared__ float sQC[80];
  __shared__ float sOther[200];     // [0..7] dense, [8..199] sparse embeds
  __shared__ float sH2T[40 * 41];   // [j][l]
  __shared__ float sAtt[40];

  const int t = threadIdx.x;        // 0..319
  const int b = blockIdx.x;
  const int wv = t >> 6, ln = t & 63, m16 = ln & 15, quad = ln >> 4;

  // ---- phase 1: gathers + zeroing ----
  if (t < 32) {
    int f = t >> 4, sub = t & 15;
    int idx = itemi[b * 2 + f];
    float4 v = *(const float4*)(embQ + ((size_t)(f * VV + idx)) * 64 + sub * 4);
    *(float4*)(sQ + f * 64 + sub * 4) = v;
  } else if (t < 80) {
    int j = t - 32, f = j >> 4, sub = j & 15;
    int idx = sparsei[b * 3 + f];
    float4 v = *(const float4*)(embS + ((size_t)(f * VV + idx)) * 64 + sub * 4);
    *(float4*)(sOther + 8 + f * 64 + sub * 4) = v;
  } else if (t < 88) {
    sOther[t - 80] = dense[b * 8 + (t - 80)];
  }
  for (int i = t; i < 1280; i += 320) {
    int r = i >> 4, sub = i & 15;
    int l = r >> 1, f = r & 1;
    int idx = seqi[b * 80 + r];
    float4 v = *(const float4*)(embQ + ((size_t)(f * VV + idx)) * 64 + sub * 4);
    ushort4 u;
    u.x = f2bf(v.x); u.y = f2bf(v.y); u.z = f2bf(v.z); u.w = f2bf(v.w);
    *(ushort4*)(sX + l * XS + f * 64 + sub * 4) = u;
  }
  for (int i = t; i < 1056; i += 320) ((unsigned*)(sX + 40 * XS))[i] = 0u;  // M-pad rows
  for (int i = t; i < 384; i += 320) {                                       // H1 K-pad cols
    int r = i >> 3, c = i & 7;
    ((unsigned*)sH1)[r * 52 + 40 + c] = 0u;
  }
  __syncthreads();

  // ---- phase 2: qconst (t<80) || q*s product (t>=80) ----
  if (t < 80) {
    float acc = ab1[t];
    const float* wq = wqcT + t * 132;
    for (int k = 0; k < 128; k += 4) {
      float4 w = *(const float4*)(wq + k);
      float4 q = *(const float4*)(sQ + k);
      acc += q.x * w.x + q.y * w.y + q.z * w.z + q.w * w.w;
    }
    sQC[t] = acc;
  } else {
    for (int i = t - 80; i < 2560; i += 240) {
      int l = i >> 6, kp = i & 63;
      unsigned sv = *(const unsigned*)(sX + l * XS + 2 * kp);
      float s0 = bf2f((unsigned short)sv);
      float s1 = bf2f((unsigned short)(sv >> 16));
      float p0 = sQ[2 * kp] * s0, p1 = sQ[2 * kp + 1] * s1;
      *(unsigned*)(sX + l * XS + 128 + 2 * kp) =
          (unsigned)f2bf(p0) | ((unsigned)f2bf(p1) << 16);
    }
  }
  __syncthreads();

  // ---- phase 3: layer1 MFMA, wave = N-tile, B-frags cached in regs ----
  {
    const int nt = wv;                 // 0..4
    short8 Bf[8];
    const unsigned short* br = WsdpT + (size_t)(nt * 16 + m16) * 256 + quad * 8;
#pragma unroll
    for (int kt = 0; kt < 8; kt++) Bf[kt] = *(const short8*)(br + kt * 32);
    const int h = nt * 16 + m16;
    float qc = sQC[h];
#pragma unroll
    for (int mt = 0; mt < 3; mt++) {
      f32x4 acc = {0.f, 0.f, 0.f, 0.f};
      const unsigned short* ar = sX + (mt * 16 + m16) * XS + quad * 8;
#pragma unroll
      for (int kt = 0; kt < 8; kt++) {
        short8 a = *(const short8*)(ar + kt * 32);
        acc = __builtin_amdgcn_mfma_f32_16x16x32_bf16(a, Bf[kt], acc, 0, 0, 0);
      }
#pragma unroll
      for (int r = 0; r < 4; r++) {
        int l = mt * 16 + quad * 4 + r;
        float z = acc[r] + qc;
        sH1[l * HS + h] = f2bf(1.f / (1.f + __expf(-z)));
      }
    }
  }
  __syncthreads();

  // ---- phase 4: layer2 MFMA: C[48x48] = H1[48x96] . W2[96x48] ----
  for (int tile = wv; tile < 9; tile += 5) {
    int mt = tile / 3, nt = tile % 3;
    f32x4 acc = {0.f, 0.f, 0.f, 0.f};
    const unsigned short* ar = sH1 + (mt * 16 + m16) * HS + quad * 8;
    const unsigned short* br = W2bT + (nt * 16 + m16) * 96 + quad * 8;
#pragma unroll
    for (int kt = 0; kt < 3; kt++) {
      short8 a = *(const short8*)(ar + kt * 32);
      short8 bb = *(const short8*)(br + kt * 32);
      acc = __builtin_amdgcn_mfma_f32_16x16x32_bf16(a, bb, acc, 0, 0, 0);
    }
    int j = nt * 16 + m16;
    if (j < 40) {
      float b2 = ab2[j];
#pragma unroll
      for (int r = 0; r < 4; r++) {
        int l = mt * 16 + quad * 4 + r;
        if (l < 40) sH2T[j * 41 + l] = 1.f / (1.f + __expf(-(acc[r] + b2)));
      }
    }
  }
  __syncthreads();

  // ---- phase 5: softmax (wave 0) || store item/other/pad cols of Xg (waves 1-4) ----
  if (wv == 0) {
    float logit = -3.0e38f;
    if (t < 40) {
      float acc = abf[0];
      for (int j = 0; j < 40; j++) acc += sH2T[j * 41 + t] * aWf[j];
      logit = (seqi[b * 80 + 2 * t] != 0) ? acc : NEG_INF_F;
    }
    float mx = logit;
    for (int off = 32; off; off >>= 1) mx = fmaxf(mx, __shfl_xor(mx, off, 64));
    float ex = (t < 40) ? __expf(logit - mx) : 0.f;
    float sm = ex;
    for (int off = 32; off; off >>= 1) sm += __shfl_xor(sm, off, 64);
    if (t < 40) sAtt[t] = ex / sm;
  } else {
    int j = t - 64;                                  // 0..255
    unsigned* xr = (unsigned*)(Xg + (size_t)b * XGS);
    if (j < 64) {
      xr[64 + j] = (unsigned)f2bf(sQ[2 * j]) | ((unsigned)f2bf(sQ[2 * j + 1]) << 16);
    } else if (j < 164) {
      int p = j - 64;
      xr[128 + p] = (unsigned)f2bf(sOther[2 * p]) | ((unsigned)f2bf(sOther[2 * p + 1]) << 16);
    } else if (j < 176) {
      xr[228 + (j - 164)] = 0u;                      // K-pad cols 456..479
    }
  }
  __syncthreads();

  // ---- phase 6: attention pool -> Xg cols 0..127 ----
  if (t < 128) {
    float acc = 0.f;
    for (int l = 0; l < 40; l++) acc += sAtt[l] * bf2f(sX[l * XS + t]);
    Xg[(size_t)b * XGS + t] = f2bf(acc);
  }
}

// ---------------- kernel B: batched FFN GEMM, 32 rows per block ----------------

__launch_bounds__(320, 1)
__global__ void din_ffn(const unsigned short* __restrict__ Xg,
                        const unsigned short* __restrict__ W1fT, const float* __restrict__ b1p,
                        const float* __restrict__ fa1,
                        const unsigned short* __restrict__ W2fT, const float* __restrict__ fb2,
                        const float* __restrict__ fa2,
                        const float* __restrict__ oW, const float* __restrict__ ob,
                        float* __restrict__ out) {
  __shared__ __align__(16) unsigned short sXB[32 * 488];
  __shared__ __align__(16) unsigned short sH1B[32 * HS];
  __shared__ float sH2B[32 * 41];
  const int t = threadIdx.x, blk = blockIdx.x;
  const int wv = t >> 6, ln = t & 63, m16 = ln & 15, quad = ln >> 4;

  // stage X tile (32 rows x 480 bf16) + zero H1 K-pad
  for (int i = t; i < 32 * 60; i += 320) {
    int r = i / 60, c = i % 60;
    *(uint4*)(sXB + r * 488 + c * 8) = *(const uint4*)(Xg + (size_t)(blk * 32 + r) * XGS + c * 8);
  }
  for (int i = t; i < 32 * 8; i += 320) {
    int r = i >> 3, c = i & 7;
    ((unsigned*)sH1B)[r * 52 + 40 + c] = 0u;
  }
  __syncthreads();

  // GEMM1: [32x480] @ [480x80], wave = N-tile, B cached in regs
  {
    int nt = wv, h = nt * 16 + m16;
    short8 Bf[15];
    const unsigned short* br = W1fT + (size_t)h * 480 + quad * 8;
#pragma unroll
    for (int kt = 0; kt < 15; kt++) Bf[kt] = *(const short8*)(br + kt * 32);
    float b1v = b1p[h], a1v = fa1[h];
#pragma unroll
    for (int mt = 0; mt < 2; mt++) {
      f32x4 acc = {0.f, 0.f, 0.f, 0.f};
      const unsigned short* ar = sXB + (mt * 16 + m16) * 488 + quad * 8;
#pragma unroll
      for (int kt = 0; kt < 15; kt++) {
        short8 a = *(const short8*)(ar + kt * 32);
        acc = __builtin_amdgcn_mfma_f32_16x16x32_bf16(a, Bf[kt], acc, 0, 0, 0);
      }
#pragma unroll
      for (int r = 0; r < 4; r++) {
        int l = mt * 16 + quad * 4 + r;
        float z = acc[r] + b1v;
        z = z > 0.f ? z : a1v * z;
        sH1B[l * HS + h] = f2bf(z);
      }
    }
  }
  __syncthreads();

  // GEMM2: [32x96] @ [96x48]
  for (int tile = wv; tile < 6; tile += 5) {
    int mt = tile / 3, nt = tile % 3;
    f32x4 acc = {0.f, 0.f, 0.f, 0.f};
    const unsigned short* ar = sH1B + (mt * 16 + m16) * HS + quad * 8;
    const unsigned short* br = W2fT + (nt * 16 + m16) * 96 + quad * 8;
#pragma unroll
    for (int kt = 0; kt < 3; kt++) {
      short8 a = *(const short8*)(ar + kt * 32);
      short8 bb = *(const short8*)(br + kt * 32);
      acc = __builtin_amdgcn_mfma_f32_16x16x32_bf16(a, bb, acc, 0, 0, 0);
    }
    int j = nt * 16 + m16;
    if (j < 40) {
      float b2 = fb2[j], a2 = fa2[j];
#pragma unroll
      for (int r = 0; r < 4; r++) {
        int l = mt * 16 + quad * 4 + r;
        float z = acc[r] + b2;
        sH2B[l * 41 + j] = z > 0.f ? z : a2 * z;
      }
    }
  }
  __syncthreads();

  // final dot(40) + sigmoid
  if (t < 32) {
    float acc = ob[0];
    for (int j = 0; j < 40; j++) acc += sH2B[t * 41 + j] * oW[j];
    out[blk * 32 + t] = 1.f / (1.f + __expf(-acc));
  }
}

// ---------------- launch ----------------

extern "C" void kernel_launch(void* const* d_in, const int* in_sizes, int n_in,
                              void* d_out, int out_size, void* d_ws, size_t ws_size,
                              hipStream_t stream) {
  const float* dense  = (const float*)d_in[0];
  const int*   sparsei = (const int*)d_in[1];
  const int*   seqi   = (const int*)d_in[2];
  const int*   itemi  = (const int*)d_in[3];
  const float* embS   = (const float*)d_in[4];
  const float* embQ   = (const float*)d_in[5];
  const float* aW1    = (const float*)d_in[6];
  const float* ab1    = (const float*)d_in[7];
  const float* aW2    = (const float*)d_in[8];
  const float* ab2    = (const float*)d_in[9];
  const float* aWf    = (const float*)d_in[10];
  const float* abf    = (const float*)d_in[11];
  const float* bng    = (const float*)d_in[12];
  const float* bnb    = (const float*)d_in[13];
  const float* bnm    = (const float*)d_in[14];
  const float* bnv    = (const float*)d_in[15];
  const float* fW1    = (const float*)d_in[16];
  const float* fb1    = (const float*)d_in[17];
  const float* fa1    = (const float*)d_in[18];
  const float* fW2    = (const float*)d_in[19];
  const float* fb2    = (const float*)d_in[20];
  const float* fa2    = (const float*)d_in[21];
  const float* oW     = (const float*)d_in[22];
  const float* ob     = (const float*)d_in[23];
  float* out = (float*)d_out;

  float* ws = (float*)d_ws;
  float* wqcT = ws;                                          // 10560 f
  float* b1p  = ws + 10560;                                  // 80 f
  unsigned short* WsdpT = (unsigned short*)(ws + 10640);     // 20480 u16 = 10240 f
  unsigned short* W2bT  = (unsigned short*)(ws + 20880);     // 4608 u16 = 2304 f
  unsigned short* W2fT  = (unsigned short*)(ws + 23184);     // 4608 u16 = 2304 f
  unsigned short* W1fT  = (unsigned short*)(ws + 25488);     // 38400 u16 = 19200 f
  unsigned short* Xg    = (unsigned short*)(ws + 44688);     // 8192*480 u16

  prep_all<<<226, 256, 0, stream>>>(aW1, wqcT, WsdpT, aW2, W2bT, fW2, W2fT,
                                    fW1, bng, bnv, W1fT);
  prep_b1p<<<80, 512, 0, stream>>>(fW1, fb1, bng, bnb, bnm, bnv, b1p);
  din_att<<<BB, 320, 0, stream>>>(dense, sparsei, seqi, itemi, embS, embQ,
                                  wqcT, WsdpT, W2bT, ab1, ab2, aWf, abf, Xg);
  din_ffn<<<256, 320, 0, stream>>>(Xg, W1fT, b1p, fa1, W2fT, fb2, fa2, oW, ob, out);
}

// Round 4
// 365.578 us; speedup vs baseline: 2.5497x; 1.3893x over previous
//
#include <hip/hip_runtime.h>

#define BB 8192
#define LL 40
#define VV 100000
#define NEG_INF_F (-4294967295.0f)
#define XS 264    // attention A-tile row stride (bf16)
#define HS 104    // H1 row stride (bf16), K padded 80->96
#define XGS 480   // global info_all row stride (bf16), K padded 456->480

typedef __attribute__((ext_vector_type(8))) short short8;
typedef __attribute__((ext_vector_type(4))) float f32x4;

__device__ __forceinline__ unsigned short f2bf(float f) {
  unsigned u = __float_as_uint(f);
  u += 0x7FFFu + ((u >> 16) & 1u);
  return (unsigned short)(u >> 16);
}
__device__ __forceinline__ float bf2f(unsigned short s) {
  return __uint_as_float(((unsigned)s) << 16);
}

// ---------------- prep (fused, parallel) ----------------
// bid<40 : attention W1 -> wqcT fp32[80][132], WsdpT bf16[80][256]
// bid<58 : attention W2 -> W2bT bf16[48][96] (zero-padded)
// bid<76 : ffn W2       -> W2fT bf16[48][96] (zero-padded)
// bid<226: ffn W1 (BN-folded) -> W1fT bf16[80][480] (k>=456 zero)
// else   : b1p[n] (BN-folded ffn bias), n = bid-226
__global__ void prep_all(const float* __restrict__ W1, float* __restrict__ wqcT,
                         unsigned short* __restrict__ WsdpT,
                         const float* __restrict__ aW2, unsigned short* __restrict__ W2bT,
                         const float* __restrict__ fW2, unsigned short* __restrict__ W2fT,
                         const float* __restrict__ fW1, const float* __restrict__ g,
                         const float* __restrict__ vr, unsigned short* __restrict__ W1fT,
                         const float* __restrict__ fb1, const float* __restrict__ be,
                         const float* __restrict__ mn, float* __restrict__ b1p) {
  __shared__ float red[4];
  int bid = blockIdx.x, t = threadIdx.x;
  if (bid < 40) {
    int i = bid * 256 + t;           // exactly 10240
    int h = i >> 7, k = i & 127;
    float a = W1[k * 80 + h];
    float b = W1[(128 + k) * 80 + h];
    float c = W1[(256 + k) * 80 + h];
    float d = W1[(384 + k) * 80 + h];
    wqcT[h * 132 + k] = a + c;
    WsdpT[h * 256 + k] = f2bf(b - c);
    WsdpT[h * 256 + 128 + k] = f2bf(d);
  } else if (bid < 58) {
    int i = (bid - 40) * 256 + t;    // exactly 4608
    int n = i / 96, k = i % 96;
    W2bT[i] = (n < 40 && k < 80) ? f2bf(aW2[k * 40 + n]) : (unsigned short)0;
  } else if (bid < 76) {
    int i = (bid - 58) * 256 + t;
    int n = i / 96, k = i % 96;
    W2fT[i] = (n < 40 && k < 80) ? f2bf(fW2[k * 40 + n]) : (unsigned short)0;
  } else if (bid < 226) {
    int i = (bid - 76) * 256 + t;    // exactly 38400
    int n = i / 480, k = i % 480;
    float v = 0.f;
    if (k < 456) v = fW1[k * 80 + n] * g[k] * rsqrtf(vr[k] + 1e-3f);
    W1fT[i] = f2bf(v);
  } else {
    int n = bid - 226;               // 0..79
    float p = 0.f;
    for (int k = t; k < 456; k += 256) {
      float sc = g[k] * rsqrtf(vr[k] + 1e-3f);
      p += (be[k] - mn[k] * sc) * fW1[k * 80 + n];
    }
    for (int off = 32; off; off >>= 1) p += __shfl_xor(p, off, 64);
    if ((t & 63) == 0) red[t >> 6] = p;
    __syncthreads();
    if (t == 0) b1p[n] = fb1[n] + red[0] + red[1] + red[2] + red[3];
  }
}

// ---------------- kernel A: attention + pool, one row per block ----------------

__launch_bounds__(256, 3)
__global__ void din_att(const float* __restrict__ dense, const int* __restrict__ sparsei,
                        const int* __restrict__ seqi, const int* __restrict__ itemi,
                        const float* __restrict__ embS, const float* __restrict__ embQ,
                        const float* __restrict__ wqcT, const unsigned short* __restrict__ WsdpT,
                        const unsigned short* __restrict__ W2bT,
                        const float* __restrict__ ab1, const float* __restrict__ ab2,
                        const float* __restrict__ aWf, const float* __restrict__ abf,
                        unsigned short* __restrict__ Xg) {
  __shared__ __align__(16) unsigned short sX[48 * XS];
  __shared__ __align__(16) unsigned short sH1[48 * HS];
  __shared__ float sQ[128];
  __shared__ float sQC[80];
  __shared__ float sOther[200];     // [0..7] dense, [8..199] sparse embeds
  __shared__ float sH2T[40 * 41];   // [j][l]
  __shared__ float sAtt[40];

  const int t = threadIdx.x;        // 0..255
  const int b = blockIdx.x;
  const int wv = t >> 6, ln = t & 63, m16 = ln & 15, quad = ln >> 4;

  // ---- prefetch layer1 B-fragments for this wave's N-tile (nt = wv) ----
  short8 Bf[8];
  {
    const unsigned short* br = WsdpT + (size_t)(wv * 16 + m16) * 256 + quad * 8;
#pragma unroll
    for (int kt = 0; kt < 8; kt++) Bf[kt] = *(const short8*)(br + kt * 32);
  }

  // ---- phase 1: gathers + H1 K-pad zeroing ----
  if (t < 32) {
    int f = t >> 4, sub = t & 15;
    int idx = itemi[b * 2 + f];
    float4 v = *(const float4*)(embQ + ((size_t)(f * VV + idx)) * 64 + sub * 4);
    *(float4*)(sQ + f * 64 + sub * 4) = v;
  } else if (t < 80) {
    int j = t - 32, f = j >> 4, sub = j & 15;
    int idx = sparsei[b * 3 + f];
    float4 v = *(const float4*)(embS + ((size_t)(f * VV + idx)) * 64 + sub * 4);
    *(float4*)(sOther + 8 + f * 64 + sub * 4) = v;
  } else if (t < 88) {
    sOther[t - 80] = dense[b * 8 + (t - 80)];
  }
  for (int i = t; i < 1280; i += 256) {
    int r = i >> 4, sub = i & 15;
    int l = r >> 1, f = r & 1;
    int idx = seqi[b * 80 + r];
    float4 v = *(const float4*)(embQ + ((size_t)(f * VV + idx)) * 64 + sub * 4);
    ushort4 u;
    u.x = f2bf(v.x); u.y = f2bf(v.y); u.z = f2bf(v.z); u.w = f2bf(v.w);
    *(ushort4*)(sX + l * XS + f * 64 + sub * 4) = u;
  }
  for (int i = t; i < 384; i += 256) {   // H1 K-pad cols 80..95 (must be 0 or NaN-free)
    int r = i >> 3, c = i & 7;
    ((unsigned*)sH1)[r * 52 + 40 + c] = 0u;
  }
  __syncthreads();

  // ---- phase 2: qconst (t<80) || q*s product (t>=80) ----
  if (t < 80) {
    float acc = ab1[t];
    const float* wq = wqcT + t * 132;
    for (int k = 0; k < 128; k += 4) {
      float4 w = *(const float4*)(wq + k);
      float4 q = *(const float4*)(sQ + k);
      acc += q.x * w.x + q.y * w.y + q.z * w.z + q.w * w.w;
    }
    sQC[t] = acc;
  } else {
    for (int i = t - 80; i < 2560; i += 176) {
      int l = i >> 6, kp = i & 63;
      unsigned sv = *(const unsigned*)(sX + l * XS + 2 * kp);
      float s0 = bf2f((unsigned short)sv);
      float s1 = bf2f((unsigned short)(sv >> 16));
      float p0 = sQ[2 * kp] * s0, p1 = sQ[2 * kp + 1] * s1;
      *(unsigned*)(sX + l * XS + 128 + 2 * kp) =
          (unsigned)f2bf(p0) | ((unsigned)f2bf(p1) << 16);
    }
  }
  __syncthreads();

  // ---- phase 3: layer1 MFMA, wave = N-tile (B cached); waves 0-2 also cover nt=4 ----
  {
    const int h = wv * 16 + m16;
    const float qc = sQC[h];
#pragma unroll
    for (int mt = 0; mt < 3; mt++) {
      f32x4 acc = {0.f, 0.f, 0.f, 0.f};
      const unsigned short* ar = sX + (mt * 16 + m16) * XS + quad * 8;
#pragma unroll
      for (int kt = 0; kt < 8; kt++) {
        short8 a = *(const short8*)(ar + kt * 32);
        acc = __builtin_amdgcn_mfma_f32_16x16x32_bf16(a, Bf[kt], acc, 0, 0, 0);
      }
#pragma unroll
      for (int r = 0; r < 4; r++) {
        int l = mt * 16 + quad * 4 + r;
        float z = acc[r] + qc;
        sH1[l * HS + h] = f2bf(1.f / (1.f + __expf(-z)));
      }
    }
    if (wv < 3) {   // nt = 4, mt = wv
      short8 B4[8];
      const unsigned short* br = WsdpT + (size_t)(64 + m16) * 256 + quad * 8;
#pragma unroll
      for (int kt = 0; kt < 8; kt++) B4[kt] = *(const short8*)(br + kt * 32);
      f32x4 acc = {0.f, 0.f, 0.f, 0.f};
      const unsigned short* ar = sX + (wv * 16 + m16) * XS + quad * 8;
#pragma unroll
      for (int kt = 0; kt < 8; kt++) {
        short8 a = *(const short8*)(ar + kt * 32);
        acc = __builtin_amdgcn_mfma_f32_16x16x32_bf16(a, B4[kt], acc, 0, 0, 0);
      }
      int h4 = 64 + m16;
      float qc4 = sQC[h4];
#pragma unroll
      for (int r = 0; r < 4; r++) {
        int l = wv * 16 + quad * 4 + r;
        float z = acc[r] + qc4;
        sH1[l * HS + h4] = f2bf(1.f / (1.f + __expf(-z)));
      }
    }
  }
  __syncthreads();

  // ---- phase 4: layer2 MFMA: C[48x48] = H1[48x96] . W2[96x48] ----
  for (int tile = wv; tile < 9; tile += 4) {
    int mt = tile / 3, nt = tile % 3;
    f32x4 acc = {0.f, 0.f, 0.f, 0.f};
    const unsigned short* ar = sH1 + (mt * 16 + m16) * HS + quad * 8;
    const unsigned short* br = W2bT + (nt * 16 + m16) * 96 + quad * 8;
#pragma unroll
    for (int kt = 0; kt < 3; kt++) {
      short8 a = *(const short8*)(ar + kt * 32);
      short8 bb = *(const short8*)(br + kt * 32);
      acc = __builtin_amdgcn_mfma_f32_16x16x32_bf16(a, bb, acc, 0, 0, 0);
    }
    int j = nt * 16 + m16;
    if (j < 40) {
      float b2 = ab2[j];
#pragma unroll
      for (int r = 0; r < 4; r++) {
        int l = mt * 16 + quad * 4 + r;
        if (l < 40) sH2T[j * 41 + l] = 1.f / (1.f + __expf(-(acc[r] + b2)));
      }
    }
  }
  __syncthreads();

  // ---- phase 5: softmax (wave 0) || store item/other/pad cols of Xg (waves 1-3) ----
  if (wv == 0) {
    float logit = -3.0e38f;
    if (t < 40) {
      float acc = abf[0];
      for (int j = 0; j < 40; j++) acc += sH2T[j * 41 + t] * aWf[j];
      logit = (seqi[b * 80 + 2 * t] != 0) ? acc : NEG_INF_F;
    }
    float mx = logit;
    for (int off = 32; off; off >>= 1) mx = fmaxf(mx, __shfl_xor(mx, off, 64));
    float ex = (t < 40) ? __expf(logit - mx) : 0.f;
    float sm = ex;
    for (int off = 32; off; off >>= 1) sm += __shfl_xor(sm, off, 64);
    if (t < 40) sAtt[t] = ex / sm;
  } else {
    int j = t - 64;                                  // 0..191
    unsigned* xr = (unsigned*)(Xg + (size_t)b * XGS);
    if (j < 64) {
      xr[64 + j] = (unsigned)f2bf(sQ[2 * j]) | ((unsigned)f2bf(sQ[2 * j + 1]) << 16);
    } else if (j < 164) {
      int p = j - 64;
      xr[128 + p] = (unsigned)f2bf(sOther[2 * p]) | ((unsigned)f2bf(sOther[2 * p + 1]) << 16);
    } else if (j < 176) {
      xr[228 + (j - 164)] = 0u;                      // K-pad cols 456..479
    }
  }
  __syncthreads();

  // ---- phase 6: attention pool -> Xg cols 0..127 ----
  if (t < 128) {
    float acc = 0.f;
    for (int l = 0; l < 40; l++) acc += sAtt[l] * bf2f(sX[l * XS + t]);
    Xg[(size_t)b * XGS + t] = f2bf(acc);
  }
}

// ---------------- kernel B: batched FFN GEMM, 16 rows per block ----------------

__launch_bounds__(256, 3)
__global__ void din_ffn(const unsigned short* __restrict__ Xg,
                        const unsigned short* __restrict__ W1fT, const float* __restrict__ b1p,
                        const float* __restrict__ fa1,
                        const unsigned short* __restrict__ W2fT, const float* __restrict__ fb2,
                        const float* __restrict__ fa2,
                        const float* __restrict__ oW, const float* __restrict__ ob,
                        float* __restrict__ out) {
  __shared__ __align__(16) unsigned short sXB[16 * 488];
  __shared__ __align__(16) unsigned short sH1B[16 * HS];
  __shared__ float sH2B[16 * 41];
  const int t = threadIdx.x, blk = blockIdx.x;
  const int wv = t >> 6, ln = t & 63, m16 = ln & 15, quad = ln >> 4;

  // prefetch GEMM1 B-fragments for nt = wv (15 frags, K=480)
  short8 Bf[15];
  {
    const unsigned short* br = W1fT + (size_t)(wv * 16 + m16) * 480 + quad * 8;
#pragma unroll
    for (int kt = 0; kt < 15; kt++) Bf[kt] = *(const short8*)(br + kt * 32);
  }

  // stage X tile (16 rows x 480 bf16) + zero H1 K-pad
  for (int i = t; i < 960; i += 256) {
    int r = i / 60, c = i % 60;
    *(uint4*)(sXB + r * 488 + c * 8) =
        *(const uint4*)(Xg + (size_t)(blk * 16 + r) * XGS + c * 8);
  }
  if (t < 128) {
    int r = t >> 3, c = t & 7;
    ((unsigned*)sH1B)[r * 52 + 40 + c] = 0u;
  }
  __syncthreads();

  // GEMM1: [16x480] @ [480x80]; wave = N-tile; wave 0 also does nt=4
  {
    int h = wv * 16 + m16;
    f32x4 acc = {0.f, 0.f, 0.f, 0.f};
    const unsigned short* ar = sXB + m16 * 488 + quad * 8;
#pragma unroll
    for (int kt = 0; kt < 15; kt++) {
      short8 a = *(const short8*)(ar + kt * 32);
      acc = __builtin_amdgcn_mfma_f32_16x16x32_bf16(a, Bf[kt], acc, 0, 0, 0);
    }
    float b1v = b1p[h], a1v = fa1[h];
#pragma unroll
    for (int r = 0; r < 4; r++) {
      int l = quad * 4 + r;
      float z = acc[r] + b1v;
      z = z > 0.f ? z : a1v * z;
      sH1B[l * HS + h] = f2bf(z);
    }
    if (wv == 0) {   // nt = 4
      short8 B4[15];
      const unsigned short* br = W1fT + (size_t)(64 + m16) * 480 + quad * 8;
#pragma unroll
      for (int kt = 0; kt < 15; kt++) B4[kt] = *(const short8*)(br + kt * 32);
      f32x4 acc4 = {0.f, 0.f, 0.f, 0.f};
#pragma unroll
      for (int kt = 0; kt < 15; kt++) {
        short8 a = *(const short8*)(ar + kt * 32);
        acc4 = __builtin_amdgcn_mfma_f32_16x16x32_bf16(a, B4[kt], acc4, 0, 0, 0);
      }
      int h4 = 64 + m16;
      float b1v4 = b1p[h4], a1v4 = fa1[h4];
#pragma unroll
      for (int r = 0; r < 4; r++) {
        int l = quad * 4 + r;
        float z = acc4[r] + b1v4;
        z = z > 0.f ? z : a1v4 * z;
        sH1B[l * HS + h4] = f2bf(z);
      }
    }
  }
  __syncthreads();

  // GEMM2: [16x96] @ [96x48], waves 0-2
  if (wv < 3) {
    f32x4 acc = {0.f, 0.f, 0.f, 0.f};
    const unsigned short* ar = sH1B + m16 * HS + quad * 8;
    const unsigned short* br = W2fT + (wv * 16 + m16) * 96 + quad * 8;
#pragma unroll
    for (int kt = 0; kt < 3; kt++) {
      short8 a = *(const short8*)(ar + kt * 32);
      short8 bb = *(const short8*)(br + kt * 32);
      acc = __builtin_amdgcn_mfma_f32_16x16x32_bf16(a, bb, acc, 0, 0, 0);
    }
    int j = wv * 16 + m16;
    if (j < 40) {
      float b2 = fb2[j], a2 = fa2[j];
#pragma unroll
      for (int r = 0; r < 4; r++) {
        int l = quad * 4 + r;
        float z = acc[r] + b2;
        sH2B[l * 41 + j] = z > 0.f ? z : a2 * z;
      }
    }
  }
  __syncthreads();

  // final dot(40) + sigmoid
  if (t < 16) {
    float acc = ob[0];
    for (int j = 0; j < 40; j++) acc += sH2B[t * 41 + j] * oW[j];
    out[blk * 16 + t] = 1.f / (1.f + __expf(-acc));
  }
}

// ---------------- launch ----------------

extern "C" void kernel_launch(void* const* d_in, const int* in_sizes, int n_in,
                              void* d_out, int out_size, void* d_ws, size_t ws_size,
                              hipStream_t stream) {
  const float* dense  = (const float*)d_in[0];
  const int*   sparsei = (const int*)d_in[1];
  const int*   seqi   = (const int*)d_in[2];
  const int*   itemi  = (const int*)d_in[3];
  const float* embS   = (const float*)d_in[4];
  const float* embQ   = (const float*)d_in[5];
  const float* aW1    = (const float*)d_in[6];
  const float* ab1    = (const float*)d_in[7];
  const float* aW2    = (const float*)d_in[8];
  const float* ab2    = (const float*)d_in[9];
  const float* aWf    = (const float*)d_in[10];
  const float* abf    = (const float*)d_in[11];
  const float* bng    = (const float*)d_in[12];
  const float* bnb    = (const float*)d_in[13];
  const float* bnm    = (const float*)d_in[14];
  const float* bnv    = (const float*)d_in[15];
  const float* fW1    = (const float*)d_in[16];
  const float* fb1    = (const float*)d_in[17];
  const float* fa1    = (const float*)d_in[18];
  const float* fW2    = (const float*)d_in[19];
  const float* fb2    = (const float*)d_in[20];
  const float* fa2    = (const float*)d_in[21];
  const float* oW     = (const float*)d_in[22];
  const float* ob     = (const float*)d_in[23];
  float* out = (float*)d_out;

  float* ws = (float*)d_ws;
  float* wqcT = ws;                                          // 10560 f
  float* b1p  = ws + 10560;                                  // 80 f
  unsigned short* WsdpT = (unsigned short*)(ws + 10640);     // 20480 u16 = 10240 f
  unsigned short* W2bT  = (unsigned short*)(ws + 20880);     // 4608 u16 = 2304 f
  unsigned short* W2fT  = (unsigned short*)(ws + 23184);     // 4608 u16 = 2304 f
  unsigned short* W1fT  = (unsigned short*)(ws + 25488);     // 38400 u16 = 19200 f
  unsigned short* Xg    = (unsigned short*)(ws + 44688);     // 8192*480 u16

  prep_all<<<306, 256, 0, stream>>>(aW1, wqcT, WsdpT, aW2, W2bT, fW2, W2fT,
                                    fW1, bng, bnv, W1fT, fb1, bnb, bnm, b1p);
  din_att<<<BB, 256, 0, stream>>>(dense, sparsei, seqi, itemi, embS, embQ,
                                  wqcT, WsdpT, W2bT, ab1, ab2, aWf, abf, Xg);
  din_ffn<<<512, 256, 0, stream>>>(Xg, W1fT, b1p, fa1, W2fT, fb2, fa2, oW, ob, out);
}

// Round 5
// 328.093 us; speedup vs baseline: 2.8410x; 1.1143x over previous
//
#include <hip/hip_runtime.h>

#define BB 8192
#define LL 40
#define VV 100000
#define NEG_INF_F (-4294967295.0f)
#define XS 264    // sX row stride (bf16)
#define HS 104    // sH1 row stride (bf16), K padded 80->96
#define XGS 480   // global info_all row stride (bf16), K padded 456->480

typedef __attribute__((ext_vector_type(8))) short short8;
typedef __attribute__((ext_vector_type(4))) float f32x4;

__device__ __forceinline__ unsigned short f2bf(float f) {
  unsigned u = __float_as_uint(f);
  u += 0x7FFFu + ((u >> 16) & 1u);
  return (unsigned short)(u >> 16);
}
__device__ __forceinline__ float bf2f(unsigned short s) {
  return __uint_as_float(((unsigned)s) << 16);
}

// ---------------- prep (fused, parallel) ----------------
__global__ void prep_all(const float* __restrict__ W1, float* __restrict__ wqcT,
                         unsigned short* __restrict__ WsdpT,
                         const float* __restrict__ aW2, unsigned short* __restrict__ W2bT,
                         const float* __restrict__ fW2, unsigned short* __restrict__ W2fT,
                         const float* __restrict__ fW1, const float* __restrict__ g,
                         const float* __restrict__ vr, unsigned short* __restrict__ W1fT,
                         const float* __restrict__ fb1, const float* __restrict__ be,
                         const float* __restrict__ mn, float* __restrict__ b1p) {
  __shared__ float red[4];
  int bid = blockIdx.x, t = threadIdx.x;
  if (bid < 40) {
    int i = bid * 256 + t;           // exactly 10240
    int h = i >> 7, k = i & 127;
    float a = W1[k * 80 + h];
    float b = W1[(128 + k) * 80 + h];
    float c = W1[(256 + k) * 80 + h];
    float d = W1[(384 + k) * 80 + h];
    wqcT[h * 132 + k] = a + c;
    WsdpT[h * 256 + k] = f2bf(b - c);
    WsdpT[h * 256 + 128 + k] = f2bf(d);
  } else if (bid < 58) {
    int i = (bid - 40) * 256 + t;    // exactly 4608
    int n = i / 96, k = i % 96;
    W2bT[i] = (n < 40 && k < 80) ? f2bf(aW2[k * 40 + n]) : (unsigned short)0;
  } else if (bid < 76) {
    int i = (bid - 58) * 256 + t;
    int n = i / 96, k = i % 96;
    W2fT[i] = (n < 40 && k < 80) ? f2bf(fW2[k * 40 + n]) : (unsigned short)0;
  } else if (bid < 226) {
    int i = (bid - 76) * 256 + t;    // exactly 38400
    int n = i / 480, k = i % 480;
    float v = 0.f;
    if (k < 456) v = fW1[k * 80 + n] * g[k] * rsqrtf(vr[k] + 1e-3f);
    W1fT[i] = f2bf(v);
  } else {
    int n = bid - 226;               // 0..79
    float p = 0.f;
    for (int k = t; k < 456; k += 256) {
      float sc = g[k] * rsqrtf(vr[k] + 1e-3f);
      p += (be[k] - mn[k] * sc) * fW1[k * 80 + n];
    }
    for (int off = 32; off; off >>= 1) p += __shfl_xor(p, off, 64);
    if ((t & 63) == 0) red[t >> 6] = p;
    __syncthreads();
    if (t == 0) b1p[n] = fb1[n] + red[0] + red[1] + red[2] + red[3];
  }
}

// ---------------- kernel A: attention + pool, one row per block ----------------
// Manual LDS pool, 31392 B -> 5 blocks/CU.
// Layout (bytes):
//   [0      .. 21120)  sX   : 40 rows x 264 bf16  (A-reads may extend into sH1: discarded C rows)
//   [21120  .. 29440)  sH1  : 40 rows x 104 bf16  (A-reads may extend into float tail: discarded)
//   [29440  .. 31392)  floats: sQ[128] sQC[80] sOther[200] sAtt[40] sLogit[40]

__launch_bounds__(256, 5)
__global__ void din_att(const float* __restrict__ dense, const int* __restrict__ sparsei,
                        const int* __restrict__ seqi, const int* __restrict__ itemi,
                        const float* __restrict__ embS, const float* __restrict__ embQ,
                        const float* __restrict__ wqcT, const unsigned short* __restrict__ WsdpT,
                        const unsigned short* __restrict__ W2bT,
                        const float* __restrict__ ab1, const float* __restrict__ ab2,
                        const float* __restrict__ aWf, const float* __restrict__ abf,
                        unsigned short* __restrict__ Xg) {
  __shared__ __align__(16) char smem[31392];
  unsigned short* sX  = (unsigned short*)smem;             // 40 x 264
  unsigned short* sH1 = (unsigned short*)smem + 10560;     // 40 x 104
  float* sQ     = (float*)(smem + 29440);                  // 128
  float* sQC    = sQ + 128;                                // 80
  float* sOther = sQC + 80;                                // 200
  float* sAtt   = sOther + 200;                            // 40
  float* sLogit = sAtt + 40;                               // 40

  const int t = threadIdx.x;        // 0..255
  const int b = blockIdx.x;
  const int wv = t >> 6, ln = t & 63, m16 = ln & 15, quad = ln >> 4;

  // ---- prefetch layer1 B-fragments for this wave's N-tile (nt = wv) ----
  short8 Bf[8];
  {
    const unsigned short* br = WsdpT + (size_t)(wv * 16 + m16) * 256 + quad * 8;
#pragma unroll
    for (int kt = 0; kt < 8; kt++) Bf[kt] = *(const short8*)(br + kt * 32);
  }

  // ---- phase 1: gathers + zero inits ----
  if (t < 32) {
    int f = t >> 4, sub = t & 15;
    int idx = itemi[b * 2 + f];
    float4 v = *(const float4*)(embQ + ((size_t)(f * VV + idx)) * 64 + sub * 4);
    *(float4*)(sQ + f * 64 + sub * 4) = v;
  } else if (t < 80) {
    int j = t - 32, f = j >> 4, sub = j & 15;
    int idx = sparsei[b * 3 + f];
    float4 v = *(const float4*)(embS + ((size_t)(f * VV + idx)) * 64 + sub * 4);
    *(float4*)(sOther + 8 + f * 64 + sub * 4) = v;
  } else if (t < 88) {
    sOther[t - 80] = dense[b * 8 + (t - 80)];
  } else if (t < 128) {
    sLogit[t - 88] = 0.f;
  }
  for (int i = t; i < 1280; i += 256) {
    int r = i >> 4, sub = i & 15;
    int l = r >> 1, f = r & 1;
    int idx = seqi[b * 80 + r];
    float4 v = *(const float4*)(embQ + ((size_t)(f * VV + idx)) * 64 + sub * 4);
    ushort4 u;
    u.x = f2bf(v.x); u.y = f2bf(v.y); u.z = f2bf(v.z); u.w = f2bf(v.w);
    *(ushort4*)(sX + l * XS + f * 64 + sub * 4) = u;
  }
  for (int i = t; i < 320; i += 256) {   // sH1 K-pad cols 80..95, rows 0..39
    int r = i >> 3, c = i & 7;
    ((unsigned*)sH1)[r * 52 + 40 + c] = 0u;
  }
  __syncthreads();

  // ---- phase 2: qconst (t<80) || q*s product (t>=80) ----
  if (t < 80) {
    float acc = ab1[t];
    const float* wq = wqcT + t * 132;
    for (int k = 0; k < 128; k += 4) {
      float4 w = *(const float4*)(wq + k);
      float4 q = *(const float4*)(sQ + k);
      acc += q.x * w.x + q.y * w.y + q.z * w.z + q.w * w.w;
    }
    sQC[t] = acc;
  } else {
    for (int i = t - 80; i < 2560; i += 176) {
      int l = i >> 6, kp = i & 63;
      unsigned sv = *(const unsigned*)(sX + l * XS + 2 * kp);
      float s0 = bf2f((unsigned short)sv);
      float s1 = bf2f((unsigned short)(sv >> 16));
      float p0 = sQ[2 * kp] * s0, p1 = sQ[2 * kp + 1] * s1;
      *(unsigned*)(sX + l * XS + 128 + 2 * kp) =
          (unsigned)f2bf(p0) | ((unsigned)f2bf(p1) << 16);
    }
  }
  __syncthreads();

  // ---- phase 3: layer1 MFMA, wave = N-tile (B cached); waves 0-2 also cover nt=4 ----
  {
    const int h = wv * 16 + m16;
    const float qc = sQC[h];
#pragma unroll
    for (int mt = 0; mt < 3; mt++) {
      f32x4 acc = {0.f, 0.f, 0.f, 0.f};
      const unsigned short* ar = sX + (mt * 16 + m16) * XS + quad * 8;
#pragma unroll
      for (int kt = 0; kt < 8; kt++) {
        short8 a = *(const short8*)(ar + kt * 32);
        acc = __builtin_amdgcn_mfma_f32_16x16x32_bf16(a, Bf[kt], acc, 0, 0, 0);
      }
#pragma unroll
      for (int r = 0; r < 4; r++) {
        int l = mt * 16 + quad * 4 + r;
        if (l < 40) {
          float z = acc[r] + qc;
          sH1[l * HS + h] = f2bf(1.f / (1.f + __expf(-z)));
        }
      }
    }
    if (wv < 3) {   // nt = 4, mt = wv
      short8 B4[8];
      const unsigned short* br = WsdpT + (size_t)(64 + m16) * 256 + quad * 8;
#pragma unroll
      for (int kt = 0; kt < 8; kt++) B4[kt] = *(const short8*)(br + kt * 32);
      f32x4 acc = {0.f, 0.f, 0.f, 0.f};
      const unsigned short* ar = sX + (wv * 16 + m16) * XS + quad * 8;
#pragma unroll
      for (int kt = 0; kt < 8; kt++) {
        short8 a = *(const short8*)(ar + kt * 32);
        acc = __builtin_amdgcn_mfma_f32_16x16x32_bf16(a, B4[kt], acc, 0, 0, 0);
      }
      int h4 = 64 + m16;
      float qc4 = sQC[h4];
#pragma unroll
      for (int r = 0; r < 4; r++) {
        int l = wv * 16 + quad * 4 + r;
        if (l < 40) {
          float z = acc[r] + qc4;
          sH1[l * HS + h4] = f2bf(1.f / (1.f + __expf(-z)));
        }
      }
    }
  }
  __syncthreads();

  // ---- phase 4: layer2 MFMA + fused logit reduction into sLogit ----
  for (int tile = wv; tile < 9; tile += 4) {
    int mt = tile / 3, nt = tile % 3;
    f32x4 acc = {0.f, 0.f, 0.f, 0.f};
    const unsigned short* ar = sH1 + (mt * 16 + m16) * HS + quad * 8;
    const unsigned short* br = W2bT + (nt * 16 + m16) * 96 + quad * 8;
#pragma unroll
    for (int kt = 0; kt < 3; kt++) {
      short8 a = *(const short8*)(ar + kt * 32);
      short8 bb = *(const short8*)(br + kt * 32);
      acc = __builtin_amdgcn_mfma_f32_16x16x32_bf16(a, bb, acc, 0, 0, 0);
    }
    int j = nt * 16 + m16;
    float b2 = (j < 40) ? ab2[j] : 0.f;
    float wf = (j < 40) ? aWf[j] : 0.f;
    float c[4];
#pragma unroll
    for (int r = 0; r < 4; r++) {
      float h2 = 1.f / (1.f + __expf(-(acc[r] + b2)));
      c[r] = (j < 40) ? h2 * wf : 0.f;    // gate garbage j-lanes (NaN-safe select)
    }
    // butterfly over m16 lanes (j within tile); quad/r fixed => per-l sums
#pragma unroll
    for (int off = 1; off < 16; off <<= 1) {
#pragma unroll
      for (int r = 0; r < 4; r++) c[r] += __shfl_xor(c[r], off, 64);
    }
    if (m16 == 0) {
#pragma unroll
      for (int r = 0; r < 4; r++) {
        int l = mt * 16 + quad * 4 + r;
        if (l < 40) atomicAdd(&sLogit[l], c[r]);
      }
    }
  }
  __syncthreads();

  // ---- phase 5: softmax (wave 0) || store item/other/pad cols of Xg (waves 1-3) ----
  if (wv == 0) {
    float logit = -3.0e38f;
    if (t < 40) {
      logit = (seqi[b * 80 + 2 * t] != 0) ? (sLogit[t] + abf[0]) : NEG_INF_F;
    }
    float mx = logit;
    for (int off = 32; off; off >>= 1) mx = fmaxf(mx, __shfl_xor(mx, off, 64));
    float ex = (t < 40) ? __expf(logit - mx) : 0.f;
    float sm = ex;
    for (int off = 32; off; off >>= 1) sm += __shfl_xor(sm, off, 64);
    if (t < 40) sAtt[t] = ex / sm;
  } else {
    int j = t - 64;                                  // 0..191
    unsigned* xr = (unsigned*)(Xg + (size_t)b * XGS);
    if (j < 64) {
      xr[64 + j] = (unsigned)f2bf(sQ[2 * j]) | ((unsigned)f2bf(sQ[2 * j + 1]) << 16);
    } else if (j < 164) {
      int p = j - 64;
      xr[128 + p] = (unsigned)f2bf(sOther[2 * p]) | ((unsigned)f2bf(sOther[2 * p + 1]) << 16);
    } else if (j < 176) {
      xr[228 + (j - 164)] = 0u;                      // K-pad cols 456..479
    }
  }
  __syncthreads();

  // ---- phase 6: attention pool -> Xg cols 0..127 ----
  if (t < 128) {
    float acc = 0.f;
    for (int l = 0; l < 40; l++) acc += sAtt[l] * bf2f(sX[l * XS + t]);
    Xg[(size_t)b * XGS + t] = f2bf(acc);
  }
}

// ---------------- kernel B: batched FFN GEMM, 16 rows per block ----------------

__launch_bounds__(256, 2)
__global__ void din_ffn(const unsigned short* __restrict__ Xg,
                        const unsigned short* __restrict__ W1fT, const float* __restrict__ b1p,
                        const float* __restrict__ fa1,
                        const unsigned short* __restrict__ W2fT, const float* __restrict__ fb2,
                        const float* __restrict__ fa2,
                        const float* __restrict__ oW, const float* __restrict__ ob,
                        float* __restrict__ out) {
  __shared__ __align__(16) unsigned short sXB[16 * 488];
  __shared__ __align__(16) unsigned short sH1B[16 * HS];
  __shared__ float sH2B[16 * 41];
  const int t = threadIdx.x, blk = blockIdx.x;
  const int wv = t >> 6, ln = t & 63, m16 = ln & 15, quad = ln >> 4;

  // prefetch GEMM1 B-fragments for nt = wv (15 frags, K=480)
  short8 Bf[15];
  {
    const unsigned short* br = W1fT + (size_t)(wv * 16 + m16) * 480 + quad * 8;
#pragma unroll
    for (int kt = 0; kt < 15; kt++) Bf[kt] = *(const short8*)(br + kt * 32);
  }

  // stage X tile (16 rows x 480 bf16) + zero H1 K-pad
  for (int i = t; i < 960; i += 256) {
    int r = i / 60, c = i % 60;
    *(uint4*)(sXB + r * 488 + c * 8) =
        *(const uint4*)(Xg + (size_t)(blk * 16 + r) * XGS + c * 8);
  }
  if (t < 128) {
    int r = t >> 3, c = t & 7;
    ((unsigned*)sH1B)[r * 52 + 40 + c] = 0u;
  }
  __syncthreads();

  // GEMM1: [16x480] @ [480x80]; wave = N-tile; wave 0 also does nt=4
  {
    int h = wv * 16 + m16;
    f32x4 acc = {0.f, 0.f, 0.f, 0.f};
    const unsigned short* ar = sXB + m16 * 488 + quad * 8;
#pragma unroll
    for (int kt = 0; kt < 15; kt++) {
      short8 a = *(const short8*)(ar + kt * 32);
      acc = __builtin_amdgcn_mfma_f32_16x16x32_bf16(a, Bf[kt], acc, 0, 0, 0);
    }
    float b1v = b1p[h], a1v = fa1[h];
#pragma unroll
    for (int r = 0; r < 4; r++) {
      int l = quad * 4 + r;
      float z = acc[r] + b1v;
      z = z > 0.f ? z : a1v * z;
      sH1B[l * HS + h] = f2bf(z);
    }
    if (wv == 0) {   // nt = 4
      short8 B4[15];
      const unsigned short* br = W1fT + (size_t)(64 + m16) * 480 + quad * 8;
#pragma unroll
      for (int kt = 0; kt < 15; kt++) B4[kt] = *(const short8*)(br + kt * 32);
      f32x4 acc4 = {0.f, 0.f, 0.f, 0.f};
#pragma unroll
      for (int kt = 0; kt < 15; kt++) {
        short8 a = *(const short8*)(ar + kt * 32);
        acc4 = __builtin_amdgcn_mfma_f32_16x16x32_bf16(a, B4[kt], acc4, 0, 0, 0);
      }
      int h4 = 64 + m16;
      float b1v4 = b1p[h4], a1v4 = fa1[h4];
#pragma unroll
      for (int r = 0; r < 4; r++) {
        int l = quad * 4 + r;
        float z = acc4[r] + b1v4;
        z = z > 0.f ? z : a1v4 * z;
        sH1B[l * HS + h4] = f2bf(z);
      }
    }
  }
  __syncthreads();

  // GEMM2: [16x96] @ [96x48], waves 0-2
  if (wv < 3) {
    f32x4 acc = {0.f, 0.f, 0.f, 0.f};
    const unsigned short* ar = sH1B + m16 * HS + quad * 8;
    const unsigned short* br = W2fT + (wv * 16 + m16) * 96 + quad * 8;
#pragma unroll
    for (int kt = 0; kt < 3; kt++) {
      short8 a = *(const short8*)(ar + kt * 32);
      short8 bb = *(const short8*)(br + kt * 32);
      acc = __builtin_amdgcn_mfma_f32_16x16x32_bf16(a, bb, acc, 0, 0, 0);
    }
    int j = wv * 16 + m16;
    if (j < 40) {
      float b2 = fb2[j], a2 = fa2[j];
#pragma unroll
      for (int r = 0; r < 4; r++) {
        int l = quad * 4 + r;
        float z = acc[r] + b2;
        sH2B[l * 41 + j] = z > 0.f ? z : a2 * z;
      }
    }
  }
  __syncthreads();

  // final dot(40) + sigmoid
  if (t < 16) {
    float acc = ob[0];
    for (int j = 0; j < 40; j++) acc += sH2B[t * 41 + j] * oW[j];
    out[blk * 16 + t] = 1.f / (1.f + __expf(-acc));
  }
}

// ---------------- launch ----------------

extern "C" void kernel_launch(void* const* d_in, const int* in_sizes, int n_in,
                              void* d_out, int out_size, void* d_ws, size_t ws_size,
                              hipStream_t stream) {
  const float* dense  = (const float*)d_in[0];
  const int*   sparsei = (const int*)d_in[1];
  const int*   seqi   = (const int*)d_in[2];
  const int*   itemi  = (const int*)d_in[3];
  const float* embS   = (const float*)d_in[4];
  const float* embQ   = (const float*)d_in[5];
  const float* aW1    = (const float*)d_in[6];
  const float* ab1    = (const float*)d_in[7];
  const float* aW2    = (const float*)d_in[8];
  const float* ab2    = (const float*)d_in[9];
  const float* aWf    = (const float*)d_in[10];
  const float* abf    = (const float*)d_in[11];
  const float* bng    = (const float*)d_in[12];
  const float* bnb    = (const float*)d_in[13];
  const float* bnm    = (const float*)d_in[14];
  const float* bnv    = (const float*)d_in[15];
  const float* fW1    = (const float*)d_in[16];
  const float* fb1    = (const float*)d_in[17];
  const float* fa1    = (const float*)d_in[18];
  const float* fW2    = (const float*)d_in[19];
  const float* fb2    = (const float*)d_in[20];
  const float* fa2    = (const float*)d_in[21];
  const float* oW     = (const float*)d_in[22];
  const float* ob     = (const float*)d_in[23];
  float* out = (float*)d_out;

  float* ws = (float*)d_ws;
  float* wqcT = ws;                                          // 10560 f
  float* b1p  = ws + 10560;                                  // 80 f
  unsigned short* WsdpT = (unsigned short*)(ws + 10640);     // 20480 u16 = 10240 f
  unsigned short* W2bT  = (unsigned short*)(ws + 20880);     // 4608 u16 = 2304 f
  unsigned short* W2fT  = (unsigned short*)(ws + 23184);     // 4608 u16 = 2304 f
  unsigned short* W1fT  = (unsigned short*)(ws + 25488);     // 38400 u16 = 19200 f
  unsigned short* Xg    = (unsigned short*)(ws + 44688);     // 8192*480 u16

  prep_all<<<306, 256, 0, stream>>>(aW1, wqcT, WsdpT, aW2, W2bT, fW2, W2fT,
                                    fW1, bng, bnv, W1fT, fb1, bnb, bnm, b1p);
  din_att<<<BB, 256, 0, stream>>>(dense, sparsei, seqi, itemi, embS, embQ,
                                  wqcT, WsdpT, W2bT, ab1, ab2, aWf, abf, Xg);
  din_ffn<<<512, 256, 0, stream>>>(Xg, W1fT, b1p, fa1, W2fT, fb2, fa2, oW, ob, out);
}